// Round 7
// baseline (393.281 us; speedup 1.0000x reference)
//
#include <hip/hip_runtime.h>
#include <stdint.h>

// Block-sparse linear: out[8192,4096] = x @ W^T + bias, W BSR 64x64 blocks.
// R10: counted-vmcnt 3-buffer pipeline on R9 geometry. Audit of R9 (147us,
// MfmaUtil 41%): wall = 2756 cy/WG-step vs components MFMA 1240 / LDS 1530 /
// L2-fetch ~1100 -> no pipe saturated; the per-step vmcnt(0) drain is
// exposed because the 2 co-resident WGs are not reliably anti-phased.
// Fix (R4's never-run design, de-risked): BK=32 -> 3 x 24KB buffers = 72KB
// (2 WG/CU keeps cross-WG TLP), per half-step {s_waitcnt vmcnt(6) [stage t
// landed, t+1 still in flight], s_barrier, sched_barrier(0) fence (rule 18),
// stage(t+2), compute(t)}. Stage is branchless (6 loads always, clamped
// indices) so vmcnt accounting is uniform. Buffer safety: buf[(t+2)%3] was
// compute(t-1)'s buffer; its ds_reads are register-consumed before any wave
// crosses the iter-t barrier. Swizzle = R7's verified 0-conflict 64B-row
// form g(r)=(r>>1)&3 on both stage and read sides. 4 waves x 128x64 tiles.

#define BATCH   8192
#define IN_F    4096
#define OUT_F   4096
#define BS      64
#define BK      32                         // k-depth per stage (half col-step)
#define NROW    64
#define NNZB    2048
#define BM      256                        // batch rows per workgroup
#define LDS_A_BYTES (BM * BK * 2)          // 16384
#define LDS_B_BYTES (2 * BS * BK * 2)      // 8192 (two W half-blocks)
#define BUF_BYTES   (LDS_A_BYTES + LDS_B_BYTES)   // 24576
#define NBUF    3                          // 73728 B total; 2 WG/CU <= 160KB

typedef float f32x4 __attribute__((ext_vector_type(4)));
typedef short s16x8 __attribute__((ext_vector_type(8)));   // 8 x bf16

__device__ __forceinline__ void async_copy16(const void* g, void* l) {
  // global -> LDS direct DMA, 16 B/lane. LDS dest = wave base + lane*16.
  __builtin_amdgcn_global_load_lds(
      (__attribute__((address_space(1))) void*)g,
      (__attribute__((address_space(3))) void*)l, 16, 0, 0);
}

__device__ __forceinline__ unsigned short f32_to_bf16(float f) {
  union { float f; uint32_t u; } v; v.f = f;
  return (unsigned short)((v.u + 0x7FFFu + ((v.u >> 16) & 1u)) >> 16);
}

// Single fused cvt for x and values (one launch instead of two).
__global__ void cvt_kernel(const float4* __restrict__ xin,
                           const float4* __restrict__ win,
                           ushort4* __restrict__ xout,
                           ushort4* __restrict__ wout, int nx4, int ntot4) {
  int i = blockIdx.x * blockDim.x + threadIdx.x;
  if (i >= ntot4) return;
  const float4* src; ushort4* dst; int j;
  if (i < nx4) { src = xin; dst = xout; j = i; }
  else         { src = win; dst = wout; j = i - nx4; }
  float4 v = src[j];
  ushort4 o;
  o.x = f32_to_bf16(v.x); o.y = f32_to_bf16(v.y);
  o.z = f32_to_bf16(v.z); o.w = f32_to_bf16(v.w);
  dst[j] = o;
}

// GEMM: grid (NROW/2=32 pairs, BATCH/BM=32), block 256 = 4 waves.
// Pair p -> rows rA=(p>>1)*4+(p&1), rB=rA+2 (same parity -> same cols in
// this dataset; merge table handles arbitrary overlap).
// Wave w: wm=w&1 (128-row m-half), wn=w>>1 (block-row of the pair).
// Per wave output tile: 128 x 64 (acc[8][4] f32x4).
__global__ __launch_bounds__(256, 2) void bsr_gemm_pair_kernel(
    const unsigned short* __restrict__ xb,   // bf16 [BATCH][IN_F]
    const unsigned short* __restrict__ wb,   // bf16 [NNZB][64][64] ([n][k])
    const float* __restrict__ bias,
    const int* __restrict__ crow,
    const int* __restrict__ cols,
    float* __restrict__ out) {
  __shared__ alignas(16) char smem[NBUF * BUF_BYTES];

  const int tid = threadIdx.x;
  const int w   = tid >> 6;        // wave 0..3
  const int l   = tid & 63;        // lane
  const int wm  = w & 1;           // m-half (128 rows)
  const int wn  = w >> 1;          // block-row within pair (0=A,1=B)
  const int p   = blockIdx.x;
  const int rA  = ((p >> 1) << 2) + (p & 1);
  const int rB  = rA + 2;
  const int m0  = blockIdx.y * BM;

  const int startA = crow[rA], endA = crow[rA + 1];
  const int startB = crow[rB], endB = crow[rB + 1];

  const int lr = l & 15;           // MFMA m/n index within 16
  const int q  = l >> 4;           // quad 0..3 (k-chunk owner)

  // Preload both sorted col lists into lane registers (<=64 entries each).
  int cvA = (startA + l < endA) ? cols[startA + l] : 0;
  int cvB = (startB + l < endB) ? cols[startB + l] : 0;

  // ---- Precompute merged step table into lane-indexed registers. ----
  // Lane t holds step t: col (myc) and packed {sA, sB, hasA, hasB} (mypk).
  // sA/sB CLAMPED valid indices -> staging is branchless/uniform.
  int myc = 0, mypk = 0;
  int nt = 0;
  {
    int ia = startA, ib = startB;
    const int clA = (endA > startA) ? endA - 1 : 0;
    const int clB = (endB > startB) ? endB - 1 : 0;
    while ((ia < endA) || (ib < endB)) {
      const int ca = (ia < endA) ? __shfl(cvA, ia - startA) : 0x7fffffff;
      const int cb = (ib < endB) ? __shfl(cvB, ib - startB) : 0x7fffffff;
      const int c  = min(ca, cb);
      const int hA = (ca == c);
      const int hB = (cb == c);
      const int sA = hA ? ia : clA;
      const int sB = hB ? ib : clB;
      if (nt == l) { myc = c; mypk = sA | (sB << 12) | (hA << 24) | (hB << 25); }
      ia += hA; ib += hB; ++nt;
    }
  }

  f32x4 acc[8][4];
#pragma unroll
  for (int mi = 0; mi < 8; ++mi)
#pragma unroll
    for (int ni = 0; ni < 4; ++ni) {
      f32x4 z = {0.f, 0.f, 0.f, 0.f};
      acc[mi][ni] = z;
    }

  // Staging lane roles (256 threads, 64B rows, R7-verified swizzle):
  // per issue: row = tid>>2, slot = tid&3; global 16B chunk = slot ^ g(row),
  // g(r) = (r>>1)&3  ->  (tid&3) ^ ((tid>>3)&3). Row offsets per issue are
  // multiples of 16 -> g unchanged; one formula serves A and B.
  const int swz8 = (((tid & 3) ^ ((tid >> 3) & 3)) << 3);      // elements
  const unsigned short* agbase =
      xb + (size_t)(m0 + (tid >> 2)) * IN_F + swz8;            // + c*64 + k0
  const int bgoff = ((tid >> 2) << 6) + swz8;                  // elements
  char* const alds = smem + tid * 16;                          // + buf off
  char* const blds = smem + LDS_A_BYTES + tid * 16;            // + buf off

  // Issue the 6 global_load_lds for half-step h into buffer buf.
  // A: 4 issues x 4KB (64 rows each); B: 1 issue per block x 2 blocks.
  auto stage = [&](int h, int buf) {
    const int t  = h >> 1;
    const int k0 = (h & 1) << 5;                               // 0 or 32
    const int c  = __shfl(myc, t);
    const int pk = __shfl(mypk, t);
    const int sA = pk & 0xfff;
    const int sB = (pk >> 12) & 0xfff;
    char* const al = alds + buf * BUF_BYTES;
    char* const bl = blds + buf * BUF_BYTES;
    const unsigned short* ag = agbase + (size_t)c * BS + k0;
#pragma unroll
    for (int it = 0; it < 4; ++it)                 // A: 256 rows x 64 B
      async_copy16(ag + (size_t)(it * 64) * IN_F, al + it * 4096);
    async_copy16(wb + ((size_t)sA << 12) + bgoff + k0, bl);        // block rA
    async_copy16(wb + ((size_t)sB << 12) + bgoff + k0, bl + 4096); // block rB
  };

  // ---- 3-buffer counted-vmcnt pipeline over half-steps. ----
  // Iter h: [vmcnt(6): stage(h) landed, stage(h+1) in flight] [s_barrier:
  // all waves' stage(h) landed AND all compute(h-1) reads consumed]
  // [sched_barrier: nothing hoists above the barrier] [stage(h+2) into
  // buf[(h+2)%3] = compute(h-1)'s buffer, now free] [compute(h)].
  const int nh = nt << 1;
  if (nh > 0) stage(0, 0);
  if (nh > 1) stage(1, 1);
  int cur = 0, nx2 = 2;
  for (int h = 0; h < nh; ++h) {
    if (h + 1 < nh) {
      asm volatile("s_waitcnt vmcnt(6)" ::: "memory");
    } else {
      asm volatile("s_waitcnt vmcnt(0)" ::: "memory");
    }
    __builtin_amdgcn_s_barrier();
    __builtin_amdgcn_sched_barrier(0);

    if (h + 2 < nh) stage(h + 2, nx2);

    const int pk = __shfl(mypk, h >> 1);
    const char* const cbase = smem + cur * BUF_BYTES;
    if ((pk >> (24 + wn)) & 1) {                   // this wave's row has col c
      __builtin_amdgcn_s_setprio(1);
      // LDS slot of global chunk q for row r: q ^ ((r>>1)&3); rows used
      // here have r mod 16 == lr -> slot = q ^ ((lr>>1)&3).
      const int chunk = ((q ^ ((lr >> 1) & 3)) << 4);          // bytes
      s16x8 af[8], bf[4];
#pragma unroll
      for (int mi = 0; mi < 8; ++mi)   // A[m][k], swizzled chunk
        af[mi] = *(const s16x8*)(cbase +
                   ((wm << 7) + (mi << 4) + lr) * 64 + chunk);
#pragma unroll
      for (int ni = 0; ni < 4; ++ni)   // B^T[n][k], block wn
        bf[ni] = *(const s16x8*)(cbase + LDS_A_BYTES + (wn << 12) +
                   ((ni << 4) + lr) * 64 + chunk);
#pragma unroll
      for (int mi = 0; mi < 8; ++mi)
#pragma unroll
        for (int ni = 0; ni < 4; ++ni)
          acc[mi][ni] = __builtin_amdgcn_mfma_f32_16x16x32_bf16(
              af[mi], bf[ni], acc[mi][ni], 0, 0, 0);
      __builtin_amdgcn_s_setprio(0);
    }
    cur = (cur == 2) ? 0 : cur + 1;
    nx2 = (nx2 == 2) ? 0 : nx2 + 1;
  }

  // Epilogue: C/D layout col=lr, row=q*4+reg. Add bias, store fp32.
  const int rW = wn ? rB : rA;
  const int colg = (rW << 6) + lr;
#pragma unroll
  for (int ni = 0; ni < 4; ++ni) {
    const float bv = bias[colg + (ni << 4)];
#pragma unroll
    for (int mi = 0; mi < 8; ++mi) {
      float* op = out +
          (size_t)(m0 + (wm << 7) + (mi << 4) + (q << 2)) * OUT_F +
          colg + (ni << 4);
#pragma unroll
      for (int e = 0; e < 4; ++e)
        op[(size_t)e * OUT_F] = acc[mi][ni][e] + bv;
    }
  }
}

// Safety net if ws_size < 84 MB: naive fp32, one thread per output element.
__global__ void fallback_kernel(const float* __restrict__ x,
                                const float* __restrict__ vals,
                                const float* __restrict__ bias,
                                const int* __restrict__ crow,
                                const int* __restrict__ cols,
                                float* __restrict__ out) {
  int idx = blockIdx.x * 256 + threadIdx.x;
  int m = idx >> 12;
  int n = idx & 4095;
  int r = n >> 6, nl = n & 63;
  float s = 0.f;
  int e = crow[r + 1];
  for (int i = crow[r]; i < e; ++i) {
    const float* xp = x + (size_t)m * IN_F + cols[i] * 64;
    const float* wp = vals + ((size_t)i << 12) + nl * 64;
    for (int k = 0; k < 64; ++k) s += xp[k] * wp[k];
  }
  out[idx] = s + bias[n];
}

extern "C" void kernel_launch(void* const* d_in, const int* in_sizes, int n_in,
                              void* d_out, int out_size, void* d_ws,
                              size_t ws_size, hipStream_t stream) {
  const float* x    = (const float*)d_in[0];
  const float* vals = (const float*)d_in[1];
  const float* bias = (const float*)d_in[2];
  const int*   crow = (const int*)d_in[3];
  const int*   cols = (const int*)d_in[4];
  float* out = (float*)d_out;

  const size_t x_elems = (size_t)BATCH * IN_F;       // 33.5M
  const size_t w_elems = (size_t)NNZB * BS * BS;     // 8.4M
  const size_t need = (x_elems + w_elems) * 2;       // bf16 bytes, ~84 MB

  if (ws_size >= need) {
    unsigned short* xb = (unsigned short*)d_ws;
    unsigned short* wbp = xb + x_elems;
    const int nx4 = (int)(x_elems / 4);
    const int ntot4 = (int)((x_elems + w_elems) / 4);
    cvt_kernel<<<(ntot4 + 255) / 256, 256, 0, stream>>>(
        (const float4*)x, (const float4*)vals,
        (ushort4*)xb, (ushort4*)wbp, nx4, ntot4);
    dim3 grid(NROW / 2, BATCH / BM);  // pair-fast: same x-slab hot in L2
    bsr_gemm_pair_kernel<<<grid, 256, 0, stream>>>(xb, wbp, bias, crow, cols,
                                                   out);
  } else {
    fallback_kernel<<<(BATCH * OUT_F) / 256, 256, 0, stream>>>(
        x, vals, bias, crow, cols, out);
  }
}